// Round 16
// baseline (179.367 us; speedup 1.0000x reference)
//
#include <hip/hip_runtime.h>

#define RCUT 6.0f
#define NPREP 288

typedef _Float16 h2v __attribute__((ext_vector_type(2)));
typedef _Float16 h8  __attribute__((ext_vector_type(8)));
typedef float    f4  __attribute__((ext_vector_type(4)));

__device__ __forceinline__ float fast_tanh(float x) {
    float e = __expf(2.0f * x);              // inf for large x -> tanh=1
    return 1.0f - 2.0f * __builtin_amdgcn_rcpf(e + 1.0f);
}

__device__ __forceinline__ h2v pkh(float a, float b) {
#if __has_builtin(__builtin_amdgcn_cvt_pkrtz)
    union { __fp16 __attribute__((ext_vector_type(2))) r; h2v h; } u;
    u.r = __builtin_amdgcn_cvt_pkrtz(a, b);
    return u.h;
#else
    h2v r; r.x = (_Float16)a; r.y = (_Float16)b; return r;
#endif
}

union SMem {
    struct {
        float s_w0[2][16], s_b0[2][16];
        __align__(16) _Float16 s_srn[512];
        __align__(16) _Float16 s_cf[4][512];
        __align__(16) _Float16 s_h1[128][32];
        unsigned short s_nbr[512];
        float s_g[4][4][64];
        float s_g4[256];
        __align__(16) _Float16 w1t[2][32][24];
        __align__(16) _Float16 w2t[2][64][40];
        int s_wcnt[4];
    } e;
    struct {
        float s_red[2][2][16][64];               // 16 KB
        __align__(16) _Float16 s_hd[16][128];    // 4 KB
        float s_sum[16][16];                     // 1 KB
    } f;
    float s_t[32][33];                           // prep scratch
};

// ---- Fused kernel: blocks [0,N)=atoms, [N,N+NPREP)=prep; last-64 finishers
//      run the fit (16 atoms/slice) after ctr==TOTAL (order-independent). ----
__global__ __launch_bounds__(256, 4) void k_fused(
    const float* __restrict__ coord, const float* __restrict__ box,
    const float* __restrict__ srmean, const float* __restrict__ srstd,
    const float* __restrict__ xrsrstd, const float* __restrict__ Gbias,
    const float* __restrict__ eW0, const float* __restrict__ eb0,
    const float* __restrict__ eW1, const float* __restrict__ eb1,
    const float* __restrict__ eW2, const float* __restrict__ eb2,
    const int* __restrict__ n1p,
    const float* __restrict__ fW0, const float* __restrict__ fW1,
    const float* __restrict__ fb0, const float* __restrict__ fb1,
    const float* __restrict__ fW2, const float* __restrict__ fb2,
    const float* __restrict__ Ebias,
    h2v* __restrict__ feat, _Float16* __restrict__ W0ht,
    _Float16* __restrict__ W1ht, unsigned int* __restrict__ counter,
    unsigned int* __restrict__ fitdone, float* __restrict__ slots,
    float* __restrict__ out, int N)
{
    const int tid = threadIdx.x;
    const int TOTAL = N + NPREP;
    __shared__ SMem sm;
    __shared__ unsigned int s_old;

    const int n1 = *n1p;
    const int wid = tid >> 6, lane = tid & 63;
    const int l15 = lane & 15, lk = lane >> 4;

    if (blockIdx.x >= (unsigned)N) {
        // ================= prep path: transpose+fp16 fit weights ============
        const int b = blockIdx.x - N;
        if (b < 256) {
            int type = b >> 7, tb = b & 127;
            int ki = tb >> 2, ci = tb & 3;
            const float* src = fW0 + (size_t)type * 131072;
            int c = tid & 31, r0 = (tid >> 5) * 4;
            #pragma unroll
            for (int q = 0; q < 4; q++)
                sm.s_t[r0 + q][c] = src[(size_t)(ki * 32 + r0 + q) * 128 + ci * 32 + c];
            __syncthreads();
            _Float16* dst = W0ht + (size_t)type * 131072;
            int kk = tid & 31, c0 = (tid >> 5) * 4;
            #pragma unroll
            for (int q = 0; q < 4; q++)
                dst[(size_t)(ci * 32 + c0 + q) * 1024 + ki * 32 + kk] = (_Float16)sm.s_t[kk][c0 + q];
        } else {
            int b2v = b - 256, type = b2v >> 4, tb = b2v & 15;
            int ki = tb >> 2, ci = tb & 3;
            const float* src = fW1 + (size_t)type * 16384;
            int c = tid & 31, r0 = (tid >> 5) * 4;
            #pragma unroll
            for (int q = 0; q < 4; q++)
                sm.s_t[r0 + q][c] = src[(size_t)(ki * 32 + r0 + q) * 128 + ci * 32 + c];
            __syncthreads();
            _Float16* dst = W1ht + (size_t)type * 16384;
            int kk = tid & 31, c0 = (tid >> 5) * 4;
            #pragma unroll
            for (int q = 0; q < 4; q++)
                dst[(size_t)(ci * 32 + c0 + q) * 128 + ki * 32 + kk] = (_Float16)sm.s_t[kk][c0 + q];
        }
    } else {
        // ================= embed path: one atom (R14 body) ==================
        const int n  = blockIdx.x;
        const int ti = (n >= n1) ? 1 : 0;

        for (int t = tid; t < 32; t += 256) { int j = t >> 4, f = t & 15;
            sm.e.s_w0[j][f] = eW0[(2 * ti + j) * 16 + f];
            sm.e.s_b0[j][f] = eb0[(2 * ti + j) * 16 + f]; }
        for (int idx = tid; idx < 1024; idx += 256) {
            int j = idx >> 9, r = idx & 511, f = r >> 5, g = r & 31;
            sm.e.w1t[j][g][f] = (_Float16)eW1[(2 * ti + j) * 512 + f * 32 + g];
        }
        for (int idx = tid; idx < 4096; idx += 256) {
            int j = idx >> 11, r = idx & 2047, g = r >> 6, c = r & 63;
            sm.e.w2t[j][c][g] = (_Float16)eW2[(2 * ti + j) * 2048 + g * 64 + c];
        }
        float b1r[2][2], b2r[2][4];
        #pragma unroll
        for (int j = 0; j < 2; j++) {
            #pragma unroll
            for (int q = 0; q < 2; q++) b1r[j][q] = eb1[(2 * ti + j) * 32 + 16 * q + l15];
            #pragma unroll
            for (int q = 0; q < 4; q++) b2r[j][q] = eb2[(2 * ti + j) * 64 + 16 * q + l15];
        }

        const float Lx = box[0], Ly = box[4], Lz = box[8];
        const float iLx = 1.0f / Lx, iLy = 1.0f / Ly, iLz = 1.0f / Lz;
        const float xn = coord[n], yn = coord[N + n], zn = coord[2 * N + n];
        const float srm  = srmean[ti];
        const float isrs = 1.0f / srstd[ti];
        const float ixrs = 1.0f / xrsrstd[ti];

        unsigned long long bal[4];
        {
            int wc = 0;
            const int mystart = wid * 256;
            #pragma unroll
            for (int r = 0; r < 4; r++) {
                int m = mystart + r * 64 + lane;
                float dx = coord[m] - xn;         dx -= Lx * rintf(dx * iLx);
                float dy = coord[N + m] - yn;     dy -= Ly * rintf(dy * iLy);
                float dz = coord[2 * N + m] - zn; dz -= Lz * rintf(dz * iLz);
                float r2 = dx * dx + dy * dy + dz * dz;
                bool pred = (r2 < RCUT * RCUT) && (m != n);
                bal[r] = __ballot(pred);
                wc += (int)__popcll(bal[r]);
            }
            if (lane == 0) sm.e.s_wcnt[wid] = wc;
        }
        __syncthreads();
        int cnt = sm.e.s_wcnt[0] + sm.e.s_wcnt[1] + sm.e.s_wcnt[2] + sm.e.s_wcnt[3];
        if (cnt > 512) cnt = 512;
        {
            int base = 0;
            for (int w = 0; w < wid; w++) base += sm.e.s_wcnt[w];
            const unsigned long long lt = (1ull << lane) - 1ull;
            const int mystart = wid * 256;
            #pragma unroll
            for (int r = 0; r < 4; r++) {
                int m = mystart + r * 64 + lane;
                if ((bal[r] >> lane) & 1ull) {
                    int pos = base + (int)__popcll(bal[r] & lt);
                    if (pos < 512) {
                        float dx = coord[m] - xn;         dx -= Lx * rintf(dx * iLx);
                        float dy = coord[N + m] - yn;     dy -= Ly * rintf(dy * iLy);
                        float dz = coord[2 * N + m] - zn; dz -= Lz * rintf(dz * iLz);
                        float r2 = dx * dx + dy * dy + dz * dz;
                        float rr = sqrtf(r2);
                        float rinv = __builtin_amdgcn_rcpf(rr);
                        float u  = rr * (1.0f / RCUT);
                        float u3 = u * u * u;
                        float sw_ = ((-6.0f * u + 15.0f) * u - 10.0f) * u3 + 1.0f;
                        float sr  = sw_ * rinv;
                        float crs = sr * rinv * ixrs + 1e-15f;
                        sm.e.s_srn[pos]   = (_Float16)((sr - srm) * isrs);
                        sm.e.s_cf[0][pos] = (_Float16)(sr * isrs);
                        sm.e.s_cf[1][pos] = (_Float16)(crs * dx);
                        sm.e.s_cf[2][pos] = (_Float16)(crs * dy);
                        sm.e.s_cf[3][pos] = (_Float16)(crs * dz);
                        sm.e.s_nbr[pos]   = (unsigned short)m;
                    }
                }
                base += (int)__popcll(bal[r]);
            }
        }
        __syncthreads();
        const int ntiles = (cnt + 127) >> 7;
        for (int i = cnt + tid; i < ntiles * 128; i += 256) {
            sm.e.s_srn[i] = (_Float16)0.0f; sm.e.s_nbr[i] = 0;
            sm.e.s_cf[0][i] = (_Float16)0.0f; sm.e.s_cf[1][i] = (_Float16)0.0f;
            sm.e.s_cf[2][i] = (_Float16)0.0f; sm.e.s_cf[3][i] = (_Float16)0.0f;
        }
        __syncthreads();

        const f4 zf4 = {0.0f, 0.0f, 0.0f, 0.0f};
        float gk[4][4] = {};

        for (int t = 0; t < ntiles; t++) {
            const int t128 = t << 7;
            #pragma unroll
            for (int mt2 = 0; mt2 < 2; mt2++) {
                const int mt = 2 * wid + mt2;
                const int row = 16 * mt + l15;
                const int rp = t128 + row;
                float srn = (float)sm.e.s_srn[rp];
                int jr = (sm.e.s_nbr[rp] >= n1) ? 1 : 0;
                h8 a = {};
                if (lk < 2) {
                    const float* wp = &sm.e.s_w0[jr][8 * lk];
                    const float* bp = &sm.e.s_b0[jr][8 * lk];
                    #pragma unroll
                    for (int q = 0; q < 8; q++)
                        a[q] = (_Float16)fast_tanh(fmaf(srn, wp[q], bp[q]));
                }
                int j_r[4];
                #pragma unroll
                for (int r = 0; r < 4; r++)
                    j_r[r] = (sm.e.s_nbr[t128 + 16 * mt + 4 * lk + r] >= n1) ? 1 : 0;

                #pragma unroll
                for (int nt1 = 0; nt1 < 2; nt1++) {
                    const int c = 16 * nt1 + l15;
                    h8 b0f = {}, b1f = {};
                    if (lk < 2) {
                        b0f = *(const h8*)&sm.e.w1t[0][c][8 * lk];
                        b1f = *(const h8*)&sm.e.w1t[1][c][8 * lk];
                    }
                    f4 d0 = __builtin_amdgcn_mfma_f32_16x16x32_f16(a, b0f, zf4, 0, 0, 0);
                    f4 d1 = __builtin_amdgcn_mfma_f32_16x16x32_f16(a, b1f, zf4, 0, 0, 0);
                    #pragma unroll
                    for (int r = 0; r < 4; r++) {
                        int gp = 16 * mt + 4 * lk + r;
                        float hv = fast_tanh((j_r[r] ? d1[r] : d0[r]) + (j_r[r] ? b1r[1][nt1] : b1r[0][nt1]));
                        int e = 16 * nt1 + l15;
                        sm.e.s_h1[gp][(((e >> 3) ^ ((gp >> 1) & 3)) << 3) + (e & 7)] = (_Float16)hv;
                    }
                }
                asm volatile("" ::: "memory");

                h8 a2 = *(const h8*)&sm.e.s_h1[row][((lk ^ ((row >> 1) & 3)) << 3)];
                float cfv[4][4];
                #pragma unroll
                for (int k = 0; k < 4; k++) {
                    #pragma unroll
                    for (int r = 0; r < 4; r++)
                        cfv[k][r] = (float)sm.e.s_cf[k][t128 + 16 * mt + 4 * lk + r];
                }
                #pragma unroll
                for (int nt = 0; nt < 4; nt++) {
                    h8 w20 = *(const h8*)&sm.e.w2t[0][16 * nt + l15][8 * lk];
                    h8 w21 = *(const h8*)&sm.e.w2t[1][16 * nt + l15][8 * lk];
                    f4 e0 = __builtin_amdgcn_mfma_f32_16x16x32_f16(a2, w20, zf4, 0, 0, 0);
                    f4 e1 = __builtin_amdgcn_mfma_f32_16x16x32_f16(a2, w21, zf4, 0, 0, 0);
                    #pragma unroll
                    for (int r = 0; r < 4; r++) {
                        float ev = fast_tanh((j_r[r] ? e1[r] : e0[r]) + (j_r[r] ? b2r[1][nt] : b2r[0][nt]));
                        #pragma unroll
                        for (int k = 0; k < 4; k++)
                            gk[k][nt] = fmaf(cfv[k][r], ev, gk[k][nt]);
                    }
                }
            }
        }

        #pragma unroll
        for (int k = 0; k < 4; k++) {
            #pragma unroll
            for (int nt = 0; nt < 4; nt++) {
                float v = gk[k][nt];
                v += __shfl_xor(v, 16);
                v += __shfl_xor(v, 32);
                if (lane < 16) sm.e.s_g[wid][k][nt * 16 + lane] = v;
            }
        }
        __syncthreads();
        {
            int k = tid >> 6, c = tid & 63;
            float g = (sm.e.s_g[0][k][c] + sm.e.s_g[1][k][c]) + (sm.e.s_g[2][k][c] + sm.e.s_g[3][k][c]);
            g *= (1.0f / 64.0f);
            if (k == 0) g += Gbias[c];
            sm.e.s_g4[k * 64 + c] = g;
        }
        __syncthreads();
        {
            h2v* outp = feat + (size_t)n * 512;
            #pragma unroll
            for (int q = 0; q < 2; q++) {
                int o2 = tid + 256 * q;
                int a = o2 >> 5, c = (2 * o2) & 63;
                float ga0 = sm.e.s_g4[a],       ga1 = sm.e.s_g4[64 + a];
                float ga2 = sm.e.s_g4[128 + a], ga3 = sm.e.s_g4[192 + a];
                float s0 = ga0 * sm.e.s_g4[c];
                s0 = fmaf(ga1, sm.e.s_g4[64 + c],  s0);
                s0 = fmaf(ga2, sm.e.s_g4[128 + c], s0);
                s0 = fmaf(ga3, sm.e.s_g4[192 + c], s0);
                float s1 = ga0 * sm.e.s_g4[c + 1];
                s1 = fmaf(ga1, sm.e.s_g4[64 + c + 1],  s1);
                s1 = fmaf(ga2, sm.e.s_g4[128 + c + 1], s1);
                s1 = fmaf(ga3, sm.e.s_g4[192 + c + 1], s1);
                outp[o2] = pkh(s0, s1);
            }
        }
    }

    // ================= handoff: last 64 finishers run the fit ================
    __threadfence();
    __syncthreads();
    if (tid == 0) s_old = atomicAdd(counter, 1u);
    __syncthreads();
    if (s_old < (unsigned)(TOTAL - 64)) return;
    const int slice = (int)(s_old - (unsigned)(TOTAL - 64));
    if (tid == 0) {
        while (__hip_atomic_load(counter, __ATOMIC_ACQUIRE, __HIP_MEMORY_SCOPE_AGENT)
               < (unsigned)TOTAL)
            __builtin_amdgcn_s_sleep(8);
    }
    __syncthreads();
    __threadfence();

    // ---- fit: 16 atoms (slice*16 ..), 256 thr: wave=(kh=K-half, ch=col-half)
    {
        const _Float16* featf = (const _Float16*)feat;
        const int w  = tid >> 6;
        const int kh = w >> 1, ch = w & 1;
        const int n0 = slice * 16;
        const int ia = (n0 >= n1) ? 1 : 0;
        const f4 zf4 = {0.0f, 0.0f, 0.0f, 0.0f};

        const _Float16* Ap = featf + (size_t)(n0 + l15) * 1024 + kh * 512;
        const _Float16* B0 = W0ht + (size_t)ia * 131072 + kh * 512;
        f4 acc[4] = {zf4, zf4, zf4, zf4};
        #pragma unroll
        for (int ks = 0; ks < 16; ks++) {
            h8 a = *(const h8*)(Ap + ks * 32 + 8 * lk);
            #pragma unroll
            for (int nt = 0; nt < 4; nt++) {
                const int c = ch * 64 + nt * 16 + l15;
                h8 b = *(const h8*)(B0 + (size_t)c * 1024 + ks * 32 + 8 * lk);
                acc[nt] = __builtin_amdgcn_mfma_f32_16x16x32_f16(a, b, acc[nt], 0, 0, 0);
            }
        }
        #pragma unroll
        for (int nt = 0; nt < 4; nt++)
            #pragma unroll
            for (int r = 0; r < 4; r++)
                sm.f.s_red[kh][ch][4 * lk + r][nt * 16 + l15] = acc[nt][r];
        __syncthreads();

        {   // reduce K-halves + bias + tanh -> s_hd (row=tid>>4, 8 cols each)
            const int row = tid >> 4, c0 = (tid & 15) * 8;
            const int chh = c0 >> 6;
            #pragma unroll
            for (int q = 0; q < 8; q++) {
                int c = c0 + q, cl = c & 63;
                float v = sm.f.s_red[0][chh][row][cl] + sm.f.s_red[1][chh][row][cl];
                float h = fast_tanh(v + fb0[ia * 128 + c]);
                sm.f.s_hd[row][((((c >> 3) ^ row) & 15) << 3) + (c & 7)] = (_Float16)h;
            }
        }
        __syncthreads();

        f4 acc1[4] = {zf4, zf4, zf4, zf4};
        #pragma unroll
        for (int ks2 = 0; ks2 < 2; ks2++) {
            const int kchunk = kh * 2 + ks2;
            h8 a = *(const h8*)&sm.f.s_hd[l15][((((kchunk * 4 + lk) ^ l15) & 15) << 3)];
            const _Float16* B1 = W1ht + (size_t)ia * 16384 + kchunk * 32;
            #pragma unroll
            for (int nt = 0; nt < 4; nt++) {
                const int c = ch * 64 + nt * 16 + l15;
                h8 b = *(const h8*)(B1 + (size_t)c * 128 + 8 * lk);
                acc1[nt] = __builtin_amdgcn_mfma_f32_16x16x32_f16(a, b, acc1[nt], 0, 0, 0);
            }
        }
        __syncthreads();   // s_red reuse
        #pragma unroll
        for (int nt = 0; nt < 4; nt++)
            #pragma unroll
            for (int r = 0; r < 4; r++)
                sm.f.s_red[kh][ch][4 * lk + r][nt * 16 + l15] = acc1[nt][r];
        __syncthreads();

        {   // final: reduce + bias + tanh, x W2
            const int row = tid >> 4, c0 = (tid & 15) * 8;
            const int chh = c0 >> 6;
            float pv = 0.0f;
            #pragma unroll
            for (int q = 0; q < 8; q++) {
                int c = c0 + q, cl = c & 63;
                float v = sm.f.s_red[0][chh][row][cl] + sm.f.s_red[1][chh][row][cl];
                pv += fast_tanh(v + fb1[ia * 128 + c]) * fW2[ia * 128 + c];
            }
            sm.f.s_sum[row][tid & 15] = pv;
        }
        __syncthreads();
        if (w == 0) {
            const int row = lane >> 2, g = lane & 3;
            float s = 0.0f;
            #pragma unroll
            for (int i = 0; i < 4; i++) s += sm.f.s_sum[row][4 * g + i];
            s += __shfl_xor(s, 1);  s += __shfl_xor(s, 2);   // across g
            s += __shfl_xor(s, 4);  s += __shfl_xor(s, 8);   // across rows
            s += __shfl_xor(s, 16); s += __shfl_xor(s, 32);
            if (lane == 0) {
                float e = s + 16.0f * (fb2[ia] + Ebias[ia]);
                slots[slice] = e;
                __threadfence();
                unsigned int old2 = atomicAdd(fitdone, 1u);
                if (old2 == 63u) {
                    __threadfence();
                    float tot = 0.0f;
                    for (int i = 0; i < 64; i++)
                        tot += __hip_atomic_load(&slots[i], __ATOMIC_RELAXED, __HIP_MEMORY_SCOPE_AGENT);
                    out[0] = tot;
                }
            }
        }
    }
}

extern "C" void kernel_launch(void* const* d_in, const int* in_sizes, int n_in,
                              void* d_out, int out_size, void* d_ws, size_t ws_size,
                              hipStream_t stream) {
    const float* coord   = (const float*)d_in[0];
    const float* box     = (const float*)d_in[1];
    const float* srmean  = (const float*)d_in[2];
    const float* srstd   = (const float*)d_in[3];
    const float* xrsrstd = (const float*)d_in[4];
    const float* Gbias   = (const float*)d_in[5];
    const float* Ebias   = (const float*)d_in[6];
    const float* eW0     = (const float*)d_in[7];
    const float* eb0     = (const float*)d_in[8];
    const float* eW1     = (const float*)d_in[9];
    const float* eb1     = (const float*)d_in[10];
    const float* eW2     = (const float*)d_in[11];
    const float* eb2     = (const float*)d_in[12];
    const float* fW0     = (const float*)d_in[13];
    const float* fb0     = (const float*)d_in[14];
    const float* fW1     = (const float*)d_in[15];
    const float* fb1     = (const float*)d_in[16];
    const float* fW2     = (const float*)d_in[17];
    const float* fb2     = (const float*)d_in[18];
    const int*   n1p     = (const int*)d_in[19];

    const int N = in_sizes[0] / 3;          // 1024
    h2v*      featbuf = (h2v*)d_ws;                                       // 2 MB
    _Float16* W0ht = (_Float16*)((char*)d_ws + (size_t)2 * 1024 * 1024);  // 512 KB
    _Float16* W1ht = W0ht + 2 * 131072;                                   // 64 KB
    char* tail = (char*)d_ws + (size_t)(2 * 1024 + 512 + 64) * 1024;
    unsigned int* counter = (unsigned int*)tail;          // +0
    unsigned int* fitdone = (unsigned int*)(tail + 4);    // +4
    float*        slots   = (float*)(tail + 64);

    (void)hipMemsetAsync(tail, 0, 64, stream);
    k_fused<<<N + NPREP, 256, 0, stream>>>(coord, box, srmean, srstd, xrsrstd,
                                           Gbias, eW0, eb0, eW1, eb1, eW2, eb2,
                                           n1p, fW0, fW1, fb0, fb1, fW2, fb2,
                                           Ebias, featbuf, W0ht, W1ht,
                                           counter, fitdone, slots,
                                           (float*)d_out, N);
}

// Round 17
// 125.124 us; speedup vs baseline: 1.4335x; 1.4335x over previous
//
#include <hip/hip_runtime.h>

#define RCUT 6.0f

typedef _Float16 h2v __attribute__((ext_vector_type(2)));
typedef _Float16 h8  __attribute__((ext_vector_type(8)));
typedef float    f4  __attribute__((ext_vector_type(4)));

__device__ __forceinline__ float fast_tanh(float x) {
    float e = __expf(2.0f * x);              // inf for large x -> tanh=1
    return 1.0f - 2.0f * __builtin_amdgcn_rcpf(e + 1.0f);
}

__device__ __forceinline__ h2v pkh(float a, float b) {
#if __has_builtin(__builtin_amdgcn_cvt_pkrtz)
    union { __fp16 __attribute__((ext_vector_type(2))) r; h2v h; } u;
    u.r = __builtin_amdgcn_cvt_pkrtz(a, b);
    return u.h;
#else
    h2v r; r.x = (_Float16)a; r.y = (_Float16)b; return r;
#endif
}

union SMem {
    struct {
        float s_w0[2][16], s_b0[2][16];
        __align__(16) _Float16 s_srn[512];
        __align__(16) _Float16 s_cf[4][512];
        __align__(16) _Float16 s_h1[128][32];
        unsigned short s_nbr[512];
        float s_g[4][4][64];
        float s_g4[256];
        __align__(16) _Float16 w1t[2][32][24];
        __align__(16) _Float16 w2t[2][64][40];
        int s_wcnt[4];
    } e;
    struct {
        float s_red[2][2][16][64];               // 16 KB
        __align__(16) _Float16 s_hd[16][128];    // 4 KB
        float s_sum[16][16];                     // 1 KB
    } f;
    float s_t[32][33];                           // prep scratch
};

// Blocks [0,N): embed atom n (blocks <288 also do weight-prep after).
// Blocks [N,N+64): fit, after spinning on 32 spread counters (sum==N).
__global__ __launch_bounds__(256, 4) void k_fused(
    const float* __restrict__ coord, const float* __restrict__ box,
    const float* __restrict__ srmean, const float* __restrict__ srstd,
    const float* __restrict__ xrsrstd, const float* __restrict__ Gbias,
    const float* __restrict__ eW0, const float* __restrict__ eb0,
    const float* __restrict__ eW1, const float* __restrict__ eb1,
    const float* __restrict__ eW2, const float* __restrict__ eb2,
    const int* __restrict__ n1p,
    const float* __restrict__ fW0, const float* __restrict__ fW1,
    const float* __restrict__ fb0, const float* __restrict__ fb1,
    const float* __restrict__ fW2, const float* __restrict__ fb2,
    const float* __restrict__ Ebias,
    h2v* __restrict__ feat, _Float16* __restrict__ W0ht,
    _Float16* __restrict__ W1ht, unsigned int* __restrict__ ctr,
    unsigned int* __restrict__ fitdone, float* __restrict__ slots,
    float* __restrict__ out, int N)
{
    const int tid = threadIdx.x;
    __shared__ SMem sm;

    const int n1 = *n1p;
    const int wid = tid >> 6, lane = tid & 63;
    const int l15 = lane & 15, lk = lane >> 4;

    if (blockIdx.x >= (unsigned)N) {
        // ================= fit path: spin, then 16-atom slice ===============
        const int slice = (int)blockIdx.x - N;
        if (wid == 0) {
            for (;;) {
                unsigned v = __hip_atomic_load(&ctr[(lane & 31) * 16],
                                               __ATOMIC_ACQUIRE, __HIP_MEMORY_SCOPE_AGENT);
                unsigned s = v;
                s += __shfl_xor(s, 1);  s += __shfl_xor(s, 2);
                s += __shfl_xor(s, 4);  s += __shfl_xor(s, 8);
                s += __shfl_xor(s, 16); s += __shfl_xor(s, 32);
                if (s == 2u * (unsigned)N) break;   // 64 lanes read 32 ctrs twice
                __builtin_amdgcn_s_sleep(8);
            }
        }
        __syncthreads();
        __threadfence();

        const _Float16* featf = (const _Float16*)feat;
        const int w  = tid >> 6;
        const int kh = w >> 1, ch = w & 1;
        const int n0 = slice * 16;
        const int ia = (n0 >= n1) ? 1 : 0;
        const f4 zf4 = {0.0f, 0.0f, 0.0f, 0.0f};

        const _Float16* Ap = featf + (size_t)(n0 + l15) * 1024 + kh * 512;
        const _Float16* B0 = W0ht + (size_t)ia * 131072 + kh * 512;
        f4 acc[4] = {zf4, zf4, zf4, zf4};
        #pragma unroll
        for (int ks = 0; ks < 16; ks++) {
            h8 a = *(const h8*)(Ap + ks * 32 + 8 * lk);
            #pragma unroll
            for (int nt = 0; nt < 4; nt++) {
                const int c = ch * 64 + nt * 16 + l15;
                h8 b = *(const h8*)(B0 + (size_t)c * 1024 + ks * 32 + 8 * lk);
                acc[nt] = __builtin_amdgcn_mfma_f32_16x16x32_f16(a, b, acc[nt], 0, 0, 0);
            }
        }
        #pragma unroll
        for (int nt = 0; nt < 4; nt++)
            #pragma unroll
            for (int r = 0; r < 4; r++)
                sm.f.s_red[kh][ch][4 * lk + r][nt * 16 + l15] = acc[nt][r];
        __syncthreads();

        {
            const int row = tid >> 4, c0 = (tid & 15) * 8;
            const int chh = c0 >> 6;
            #pragma unroll
            for (int q = 0; q < 8; q++) {
                int c = c0 + q, cl = c & 63;
                float v = sm.f.s_red[0][chh][row][cl] + sm.f.s_red[1][chh][row][cl];
                float h = fast_tanh(v + fb0[ia * 128 + c]);
                sm.f.s_hd[row][((((c >> 3) ^ row) & 15) << 3) + (c & 7)] = (_Float16)h;
            }
        }
        __syncthreads();

        f4 acc1[4] = {zf4, zf4, zf4, zf4};
        #pragma unroll
        for (int ks2 = 0; ks2 < 2; ks2++) {
            const int kchunk = kh * 2 + ks2;
            h8 a = *(const h8*)&sm.f.s_hd[l15][((((kchunk * 4 + lk) ^ l15) & 15) << 3)];
            const _Float16* B1 = W1ht + (size_t)ia * 16384 + kchunk * 32;
            #pragma unroll
            for (int nt = 0; nt < 4; nt++) {
                const int c = ch * 64 + nt * 16 + l15;
                h8 b = *(const h8*)(B1 + (size_t)c * 128 + 8 * lk);
                acc1[nt] = __builtin_amdgcn_mfma_f32_16x16x32_f16(a, b, acc1[nt], 0, 0, 0);
            }
        }
        __syncthreads();
        #pragma unroll
        for (int nt = 0; nt < 4; nt++)
            #pragma unroll
            for (int r = 0; r < 4; r++)
                sm.f.s_red[kh][ch][4 * lk + r][nt * 16 + l15] = acc1[nt][r];
        __syncthreads();

        {
            const int row = tid >> 4, c0 = (tid & 15) * 8;
            const int chh = c0 >> 6;
            float pv = 0.0f;
            #pragma unroll
            for (int q = 0; q < 8; q++) {
                int c = c0 + q, cl = c & 63;
                float v = sm.f.s_red[0][chh][row][cl] + sm.f.s_red[1][chh][row][cl];
                pv += fast_tanh(v + fb1[ia * 128 + c]) * fW2[ia * 128 + c];
            }
            sm.f.s_sum[row][tid & 15] = pv;
        }
        __syncthreads();
        if (w == 0) {
            const int row = lane >> 2, g = lane & 3;
            float s = 0.0f;
            #pragma unroll
            for (int i = 0; i < 4; i++) s += sm.f.s_sum[row][4 * g + i];
            s += __shfl_xor(s, 1);  s += __shfl_xor(s, 2);
            s += __shfl_xor(s, 4);  s += __shfl_xor(s, 8);
            s += __shfl_xor(s, 16); s += __shfl_xor(s, 32);
            if (lane == 0) {
                float e = s + 16.0f * (fb2[ia] + Ebias[ia]);
                slots[slice] = e;
                __threadfence();
                unsigned int old2 = atomicAdd(fitdone, 1u);
                if (old2 == 63u) {
                    __threadfence();
                    float tot = 0.0f;
                    for (int i = 0; i < 64; i++)
                        tot += __hip_atomic_load(&slots[i], __ATOMIC_RELAXED, __HIP_MEMORY_SCOPE_AGENT);
                    out[0] = tot;
                }
            }
        }
        return;
    }

    // ================= embed path: one atom (R14 champion body) =============
    {
        const int n  = blockIdx.x;
        const int ti = (n >= n1) ? 1 : 0;

        for (int t = tid; t < 32; t += 256) { int j = t >> 4, f = t & 15;
            sm.e.s_w0[j][f] = eW0[(2 * ti + j) * 16 + f];
            sm.e.s_b0[j][f] = eb0[(2 * ti + j) * 16 + f]; }
        for (int idx = tid; idx < 1024; idx += 256) {
            int j = idx >> 9, r = idx & 511, f = r >> 5, g = r & 31;
            sm.e.w1t[j][g][f] = (_Float16)eW1[(2 * ti + j) * 512 + f * 32 + g];
        }
        for (int idx = tid; idx < 4096; idx += 256) {
            int j = idx >> 11, r = idx & 2047, g = r >> 6, c = r & 63;
            sm.e.w2t[j][c][g] = (_Float16)eW2[(2 * ti + j) * 2048 + g * 64 + c];
        }
        float b1r[2][2], b2r[2][4];
        #pragma unroll
        for (int j = 0; j < 2; j++) {
            #pragma unroll
            for (int q = 0; q < 2; q++) b1r[j][q] = eb1[(2 * ti + j) * 32 + 16 * q + l15];
            #pragma unroll
            for (int q = 0; q < 4; q++) b2r[j][q] = eb2[(2 * ti + j) * 64 + 16 * q + l15];
        }

        const float Lx = box[0], Ly = box[4], Lz = box[8];
        const float iLx = 1.0f / Lx, iLy = 1.0f / Ly, iLz = 1.0f / Lz;
        const float xn = coord[n], yn = coord[N + n], zn = coord[2 * N + n];
        const float srm  = srmean[ti];
        const float isrs = 1.0f / srstd[ti];
        const float ixrs = 1.0f / xrsrstd[ti];

        unsigned long long bal[4];
        {
            int wc = 0;
            const int mystart = wid * 256;
            #pragma unroll
            for (int r = 0; r < 4; r++) {
                int m = mystart + r * 64 + lane;
                float dx = coord[m] - xn;         dx -= Lx * rintf(dx * iLx);
                float dy = coord[N + m] - yn;     dy -= Ly * rintf(dy * iLy);
                float dz = coord[2 * N + m] - zn; dz -= Lz * rintf(dz * iLz);
                float r2 = dx * dx + dy * dy + dz * dz;
                bool pred = (r2 < RCUT * RCUT) && (m != n);
                bal[r] = __ballot(pred);
                wc += (int)__popcll(bal[r]);
            }
            if (lane == 0) sm.e.s_wcnt[wid] = wc;
        }
        __syncthreads();
        int cnt = sm.e.s_wcnt[0] + sm.e.s_wcnt[1] + sm.e.s_wcnt[2] + sm.e.s_wcnt[3];
        if (cnt > 512) cnt = 512;
        {
            int base = 0;
            for (int w = 0; w < wid; w++) base += sm.e.s_wcnt[w];
            const unsigned long long lt = (1ull << lane) - 1ull;
            const int mystart = wid * 256;
            #pragma unroll
            for (int r = 0; r < 4; r++) {
                int m = mystart + r * 64 + lane;
                if ((bal[r] >> lane) & 1ull) {
                    int pos = base + (int)__popcll(bal[r] & lt);
                    if (pos < 512) {
                        float dx = coord[m] - xn;         dx -= Lx * rintf(dx * iLx);
                        float dy = coord[N + m] - yn;     dy -= Ly * rintf(dy * iLy);
                        float dz = coord[2 * N + m] - zn; dz -= Lz * rintf(dz * iLz);
                        float r2 = dx * dx + dy * dy + dz * dz;
                        float rr = sqrtf(r2);
                        float rinv = __builtin_amdgcn_rcpf(rr);
                        float u  = rr * (1.0f / RCUT);
                        float u3 = u * u * u;
                        float sw_ = ((-6.0f * u + 15.0f) * u - 10.0f) * u3 + 1.0f;
                        float sr  = sw_ * rinv;
                        float crs = sr * rinv * ixrs + 1e-15f;
                        sm.e.s_srn[pos]   = (_Float16)((sr - srm) * isrs);
                        sm.e.s_cf[0][pos] = (_Float16)(sr * isrs);
                        sm.e.s_cf[1][pos] = (_Float16)(crs * dx);
                        sm.e.s_cf[2][pos] = (_Float16)(crs * dy);
                        sm.e.s_cf[3][pos] = (_Float16)(crs * dz);
                        sm.e.s_nbr[pos]   = (unsigned short)m;
                    }
                }
                base += (int)__popcll(bal[r]);
            }
        }
        __syncthreads();
        const int ntiles = (cnt + 127) >> 7;
        for (int i = cnt + tid; i < ntiles * 128; i += 256) {
            sm.e.s_srn[i] = (_Float16)0.0f; sm.e.s_nbr[i] = 0;
            sm.e.s_cf[0][i] = (_Float16)0.0f; sm.e.s_cf[1][i] = (_Float16)0.0f;
            sm.e.s_cf[2][i] = (_Float16)0.0f; sm.e.s_cf[3][i] = (_Float16)0.0f;
        }
        __syncthreads();

        const f4 zf4 = {0.0f, 0.0f, 0.0f, 0.0f};
        float gk[4][4] = {};

        for (int t = 0; t < ntiles; t++) {
            const int t128 = t << 7;
            #pragma unroll
            for (int mt2 = 0; mt2 < 2; mt2++) {
                const int mt = 2 * wid + mt2;
                const int row = 16 * mt + l15;
                const int rp = t128 + row;
                float srn = (float)sm.e.s_srn[rp];
                int jr = (sm.e.s_nbr[rp] >= n1) ? 1 : 0;
                h8 a = {};
                if (lk < 2) {
                    const float* wp = &sm.e.s_w0[jr][8 * lk];
                    const float* bp = &sm.e.s_b0[jr][8 * lk];
                    #pragma unroll
                    for (int q = 0; q < 8; q++)
                        a[q] = (_Float16)fast_tanh(fmaf(srn, wp[q], bp[q]));
                }
                int j_r[4];
                #pragma unroll
                for (int r = 0; r < 4; r++)
                    j_r[r] = (sm.e.s_nbr[t128 + 16 * mt + 4 * lk + r] >= n1) ? 1 : 0;

                #pragma unroll
                for (int nt1 = 0; nt1 < 2; nt1++) {
                    const int c = 16 * nt1 + l15;
                    h8 b0f = {}, b1f = {};
                    if (lk < 2) {
                        b0f = *(const h8*)&sm.e.w1t[0][c][8 * lk];
                        b1f = *(const h8*)&sm.e.w1t[1][c][8 * lk];
                    }
                    f4 d0 = __builtin_amdgcn_mfma_f32_16x16x32_f16(a, b0f, zf4, 0, 0, 0);
                    f4 d1 = __builtin_amdgcn_mfma_f32_16x16x32_f16(a, b1f, zf4, 0, 0, 0);
                    #pragma unroll
                    for (int r = 0; r < 4; r++) {
                        int gp = 16 * mt + 4 * lk + r;
                        float hv = fast_tanh((j_r[r] ? d1[r] : d0[r]) + (j_r[r] ? b1r[1][nt1] : b1r[0][nt1]));
                        int e = 16 * nt1 + l15;
                        sm.e.s_h1[gp][(((e >> 3) ^ ((gp >> 1) & 3)) << 3) + (e & 7)] = (_Float16)hv;
                    }
                }
                asm volatile("" ::: "memory");

                h8 a2 = *(const h8*)&sm.e.s_h1[row][((lk ^ ((row >> 1) & 3)) << 3)];
                float cfv[4][4];
                #pragma unroll
                for (int k = 0; k < 4; k++) {
                    #pragma unroll
                    for (int r = 0; r < 4; r++)
                        cfv[k][r] = (float)sm.e.s_cf[k][t128 + 16 * mt + 4 * lk + r];
                }
                #pragma unroll
                for (int nt = 0; nt < 4; nt++) {
                    h8 w20 = *(const h8*)&sm.e.w2t[0][16 * nt + l15][8 * lk];
                    h8 w21 = *(const h8*)&sm.e.w2t[1][16 * nt + l15][8 * lk];
                    f4 e0 = __builtin_amdgcn_mfma_f32_16x16x32_f16(a2, w20, zf4, 0, 0, 0);
                    f4 e1 = __builtin_amdgcn_mfma_f32_16x16x32_f16(a2, w21, zf4, 0, 0, 0);
                    #pragma unroll
                    for (int r = 0; r < 4; r++) {
                        float ev = fast_tanh((j_r[r] ? e1[r] : e0[r]) + (j_r[r] ? b2r[1][nt] : b2r[0][nt]));
                        #pragma unroll
                        for (int k = 0; k < 4; k++)
                            gk[k][nt] = fmaf(cfv[k][r], ev, gk[k][nt]);
                    }
                }
            }
        }

        #pragma unroll
        for (int k = 0; k < 4; k++) {
            #pragma unroll
            for (int nt = 0; nt < 4; nt++) {
                float v = gk[k][nt];
                v += __shfl_xor(v, 16);
                v += __shfl_xor(v, 32);
                if (lane < 16) sm.e.s_g[wid][k][nt * 16 + lane] = v;
            }
        }
        __syncthreads();
        {
            int k = tid >> 6, c = tid & 63;
            float g = (sm.e.s_g[0][k][c] + sm.e.s_g[1][k][c]) + (sm.e.s_g[2][k][c] + sm.e.s_g[3][k][c]);
            g *= (1.0f / 64.0f);
            if (k == 0) g += Gbias[c];
            sm.e.s_g4[k * 64 + c] = g;
        }
        __syncthreads();
        {
            h2v* outp = feat + (size_t)n * 512;
            #pragma unroll
            for (int q = 0; q < 2; q++) {
                int o2 = tid + 256 * q;
                int a = o2 >> 5, c = (2 * o2) & 63;
                float ga0 = sm.e.s_g4[a],       ga1 = sm.e.s_g4[64 + a];
                float ga2 = sm.e.s_g4[128 + a], ga3 = sm.e.s_g4[192 + a];
                float s0 = ga0 * sm.e.s_g4[c];
                s0 = fmaf(ga1, sm.e.s_g4[64 + c],  s0);
                s0 = fmaf(ga2, sm.e.s_g4[128 + c], s0);
                s0 = fmaf(ga3, sm.e.s_g4[192 + c], s0);
                float s1 = ga0 * sm.e.s_g4[c + 1];
                s1 = fmaf(ga1, sm.e.s_g4[64 + c + 1],  s1);
                s1 = fmaf(ga2, sm.e.s_g4[128 + c + 1], s1);
                s1 = fmaf(ga3, sm.e.s_g4[192 + c + 1], s1);
                outp[o2] = pkh(s0, s1);
            }
        }
    }

    // ---- prep fold: first 288 blocks transpose fit weights after embed ----
    if (blockIdx.x < 288) {
        __syncthreads();   // done with sm.e; reuse as s_t
        const int b = blockIdx.x;
        if (b < 256) {
            int type = b >> 7, tb = b & 127;
            int ki = tb >> 2, ci = tb & 3;
            const float* src = fW0 + (size_t)type * 131072;
            int c = tid & 31, r0 = (tid >> 5) * 4;
            #pragma unroll
            for (int q = 0; q < 4; q++)
                sm.s_t[r0 + q][c] = src[(size_t)(ki * 32 + r0 + q) * 128 + ci * 32 + c];
            __syncthreads();
            _Float16* dst = W0ht + (size_t)type * 131072;
            int kk = tid & 31, c0 = (tid >> 5) * 4;
            #pragma unroll
            for (int q = 0; q < 4; q++)
                dst[(size_t)(ci * 32 + c0 + q) * 1024 + ki * 32 + kk] = (_Float16)sm.s_t[kk][c0 + q];
        } else {
            int b2v = b - 256, type = b2v >> 4, tb = b2v & 15;
            int ki = tb >> 2, ci = tb & 3;
            const float* src = fW1 + (size_t)type * 16384;
            int c = tid & 31, r0 = (tid >> 5) * 4;
            #pragma unroll
            for (int q = 0; q < 4; q++)
                sm.s_t[r0 + q][c] = src[(size_t)(ki * 32 + r0 + q) * 128 + ci * 32 + c];
            __syncthreads();
            _Float16* dst = W1ht + (size_t)type * 16384;
            int kk = tid & 31, c0 = (tid >> 5) * 4;
            #pragma unroll
            for (int q = 0; q < 4; q++)
                dst[(size_t)(ci * 32 + c0 + q) * 128 + ki * 32 + kk] = (_Float16)sm.s_t[kk][c0 + q];
        }
    }

    // ---- completion signal: one add to this block's spread counter line ----
    __syncthreads();
    __threadfence();
    if (tid == 0)
        __hip_atomic_fetch_add(&ctr[(blockIdx.x & 31) * 16], 1u,
                               __ATOMIC_RELEASE, __HIP_MEMORY_SCOPE_AGENT);
}

extern "C" void kernel_launch(void* const* d_in, const int* in_sizes, int n_in,
                              void* d_out, int out_size, void* d_ws, size_t ws_size,
                              hipStream_t stream) {
    const float* coord   = (const float*)d_in[0];
    const float* box     = (const float*)d_in[1];
    const float* srmean  = (const float*)d_in[2];
    const float* srstd   = (const float*)d_in[3];
    const float* xrsrstd = (const float*)d_in[4];
    const float* Gbias   = (const float*)d_in[5];
    const float* Ebias   = (const float*)d_in[6];
    const float* eW0     = (const float*)d_in[7];
    const float* eb0     = (const float*)d_in[8];
    const float* eW1     = (const float*)d_in[9];
    const float* eb1     = (const float*)d_in[10];
    const float* eW2     = (const float*)d_in[11];
    const float* eb2     = (const float*)d_in[12];
    const float* fW0     = (const float*)d_in[13];
    const float* fb0     = (const float*)d_in[14];
    const float* fW1     = (const float*)d_in[15];
    const float* fb1     = (const float*)d_in[16];
    const float* fW2     = (const float*)d_in[17];
    const float* fb2     = (const float*)d_in[18];
    const int*   n1p     = (const int*)d_in[19];

    const int N = in_sizes[0] / 3;          // 1024
    h2v*      featbuf = (h2v*)d_ws;                                       // 2 MB
    _Float16* W0ht = (_Float16*)((char*)d_ws + (size_t)2 * 1024 * 1024);  // 512 KB
    _Float16* W1ht = W0ht + 2 * 131072;                                   // 64 KB
    char* tail = (char*)d_ws + (size_t)(2 * 1024 + 512 + 64) * 1024;
    unsigned int* ctr     = (unsigned int*)tail;          // 32 x 64B lines
    unsigned int* fitdone = (unsigned int*)(tail + 2048);
    float*        slots   = (float*)(tail + 2112);        // 64 floats

    (void)hipMemsetAsync(tail, 0, 4096, stream);
    k_fused<<<N + 64, 256, 0, stream>>>(coord, box, srmean, srstd, xrsrstd,
                                        Gbias, eW0, eb0, eW1, eb1, eW2, eb2,
                                        n1p, fW0, fW1, fb0, fb1, fW2, fb2,
                                        Ebias, featbuf, W0ht, W1ht,
                                        ctr, fitdone, slots,
                                        (float*)d_out, N);
}

// Round 18
// 39.518 us; speedup vs baseline: 4.5389x; 3.1663x over previous
//
#include <hip/hip_runtime.h>

#define RCUT 6.0f

typedef _Float16 h2v __attribute__((ext_vector_type(2)));
typedef _Float16 h8  __attribute__((ext_vector_type(8)));
typedef float    f4  __attribute__((ext_vector_type(4)));

__device__ __forceinline__ float fast_tanh(float x) {
    float e = __expf(2.0f * x);              // inf for large x -> tanh=1
    return 1.0f - 2.0f * __builtin_amdgcn_rcpf(e + 1.0f);
}

__device__ __forceinline__ h2v pkh(float a, float b) {
#if __has_builtin(__builtin_amdgcn_cvt_pkrtz)
    union { __fp16 __attribute__((ext_vector_type(2))) r; h2v h; } u;
    u.r = __builtin_amdgcn_cvt_pkrtz(a, b);
    return u.h;
#else
    h2v r; r.x = (_Float16)a; r.y = (_Float16)b; return r;
#endif
}

union SMem {
    struct {
        float s_w0[2][16], s_b0[2][16];
        __align__(16) _Float16 s_srn[512];
        __align__(16) _Float16 s_cf[4][512];
        __align__(16) _Float16 s_h1[128][32];
        unsigned short s_nbr[512];
        float s_g[4][4][64];
        float s_g4[256];
        __align__(16) _Float16 w1t[2][32][24];
        __align__(16) _Float16 w2t[2][64][40];
        int s_wcnt[4];
    } e;
    float s_t[32][33];                           // prep scratch
};

// ---- Kernel 1: grid = N exactly (one residency generation at 4 blocks/CU).
//      Every block embeds one atom; blocks 0..287 also transpose fit weights.
__global__ __launch_bounds__(256, 4) void k_embed(
    const float* __restrict__ coord, const float* __restrict__ box,
    const float* __restrict__ srmean, const float* __restrict__ srstd,
    const float* __restrict__ xrsrstd, const float* __restrict__ Gbias,
    const float* __restrict__ eW0, const float* __restrict__ eb0,
    const float* __restrict__ eW1, const float* __restrict__ eb1,
    const float* __restrict__ eW2, const float* __restrict__ eb2,
    const int* __restrict__ n1p,
    const float* __restrict__ fW0, const float* __restrict__ fW1,
    h2v* __restrict__ feat, _Float16* __restrict__ W0ht,
    _Float16* __restrict__ W1ht, unsigned int* __restrict__ counter, int N)
{
    const int tid = threadIdx.x;
    __shared__ SMem sm;

    const int n1 = *n1p;
    const int wid = tid >> 6, lane = tid & 63;
    const int l15 = lane & 15, lk = lane >> 4;

    // ================= embed path: one atom (R14 champion body) =============
    {
        const int n  = blockIdx.x;
        const int ti = (n >= n1) ? 1 : 0;

        for (int t = tid; t < 32; t += 256) { int j = t >> 4, f = t & 15;
            sm.e.s_w0[j][f] = eW0[(2 * ti + j) * 16 + f];
            sm.e.s_b0[j][f] = eb0[(2 * ti + j) * 16 + f]; }
        for (int idx = tid; idx < 1024; idx += 256) {
            int j = idx >> 9, r = idx & 511, f = r >> 5, g = r & 31;
            sm.e.w1t[j][g][f] = (_Float16)eW1[(2 * ti + j) * 512 + f * 32 + g];
        }
        for (int idx = tid; idx < 4096; idx += 256) {
            int j = idx >> 11, r = idx & 2047, g = r >> 6, c = r & 63;
            sm.e.w2t[j][c][g] = (_Float16)eW2[(2 * ti + j) * 2048 + g * 64 + c];
        }
        float b1r[2][2], b2r[2][4];
        #pragma unroll
        for (int j = 0; j < 2; j++) {
            #pragma unroll
            for (int q = 0; q < 2; q++) b1r[j][q] = eb1[(2 * ti + j) * 32 + 16 * q + l15];
            #pragma unroll
            for (int q = 0; q < 4; q++) b2r[j][q] = eb2[(2 * ti + j) * 64 + 16 * q + l15];
        }

        const float Lx = box[0], Ly = box[4], Lz = box[8];
        const float iLx = 1.0f / Lx, iLy = 1.0f / Ly, iLz = 1.0f / Lz;
        const float xn = coord[n], yn = coord[N + n], zn = coord[2 * N + n];
        const float srm  = srmean[ti];
        const float isrs = 1.0f / srstd[ti];
        const float ixrs = 1.0f / xrsrstd[ti];

        unsigned long long bal[4];
        {
            int wc = 0;
            const int mystart = wid * 256;
            #pragma unroll
            for (int r = 0; r < 4; r++) {
                int m = mystart + r * 64 + lane;
                float dx = coord[m] - xn;         dx -= Lx * rintf(dx * iLx);
                float dy = coord[N + m] - yn;     dy -= Ly * rintf(dy * iLy);
                float dz = coord[2 * N + m] - zn; dz -= Lz * rintf(dz * iLz);
                float r2 = dx * dx + dy * dy + dz * dz;
                bool pred = (r2 < RCUT * RCUT) && (m != n);
                bal[r] = __ballot(pred);
                wc += (int)__popcll(bal[r]);
            }
            if (lane == 0) sm.e.s_wcnt[wid] = wc;
        }
        __syncthreads();
        int cnt = sm.e.s_wcnt[0] + sm.e.s_wcnt[1] + sm.e.s_wcnt[2] + sm.e.s_wcnt[3];
        if (cnt > 512) cnt = 512;
        {
            int base = 0;
            for (int w = 0; w < wid; w++) base += sm.e.s_wcnt[w];
            const unsigned long long lt = (1ull << lane) - 1ull;
            const int mystart = wid * 256;
            #pragma unroll
            for (int r = 0; r < 4; r++) {
                int m = mystart + r * 64 + lane;
                if ((bal[r] >> lane) & 1ull) {
                    int pos = base + (int)__popcll(bal[r] & lt);
                    if (pos < 512) {
                        float dx = coord[m] - xn;         dx -= Lx * rintf(dx * iLx);
                        float dy = coord[N + m] - yn;     dy -= Ly * rintf(dy * iLy);
                        float dz = coord[2 * N + m] - zn; dz -= Lz * rintf(dz * iLz);
                        float r2 = dx * dx + dy * dy + dz * dz;
                        float rr = sqrtf(r2);
                        float rinv = __builtin_amdgcn_rcpf(rr);
                        float u  = rr * (1.0f / RCUT);
                        float u3 = u * u * u;
                        float sw_ = ((-6.0f * u + 15.0f) * u - 10.0f) * u3 + 1.0f;
                        float sr  = sw_ * rinv;
                        float crs = sr * rinv * ixrs + 1e-15f;
                        sm.e.s_srn[pos]   = (_Float16)((sr - srm) * isrs);
                        sm.e.s_cf[0][pos] = (_Float16)(sr * isrs);
                        sm.e.s_cf[1][pos] = (_Float16)(crs * dx);
                        sm.e.s_cf[2][pos] = (_Float16)(crs * dy);
                        sm.e.s_cf[3][pos] = (_Float16)(crs * dz);
                        sm.e.s_nbr[pos]   = (unsigned short)m;
                    }
                }
                base += (int)__popcll(bal[r]);
            }
        }
        __syncthreads();
        const int ntiles = (cnt + 127) >> 7;
        for (int i = cnt + tid; i < ntiles * 128; i += 256) {
            sm.e.s_srn[i] = (_Float16)0.0f; sm.e.s_nbr[i] = 0;
            sm.e.s_cf[0][i] = (_Float16)0.0f; sm.e.s_cf[1][i] = (_Float16)0.0f;
            sm.e.s_cf[2][i] = (_Float16)0.0f; sm.e.s_cf[3][i] = (_Float16)0.0f;
        }
        __syncthreads();

        const f4 zf4 = {0.0f, 0.0f, 0.0f, 0.0f};
        float gk[4][4] = {};

        for (int t = 0; t < ntiles; t++) {
            const int t128 = t << 7;
            #pragma unroll
            for (int mt2 = 0; mt2 < 2; mt2++) {
                const int mt = 2 * wid + mt2;
                const int row = 16 * mt + l15;
                const int rp = t128 + row;
                float srn = (float)sm.e.s_srn[rp];
                int jr = (sm.e.s_nbr[rp] >= n1) ? 1 : 0;
                h8 a = {};
                if (lk < 2) {
                    const float* wp = &sm.e.s_w0[jr][8 * lk];
                    const float* bp = &sm.e.s_b0[jr][8 * lk];
                    #pragma unroll
                    for (int q = 0; q < 8; q++)
                        a[q] = (_Float16)fast_tanh(fmaf(srn, wp[q], bp[q]));
                }
                int j_r[4];
                #pragma unroll
                for (int r = 0; r < 4; r++)
                    j_r[r] = (sm.e.s_nbr[t128 + 16 * mt + 4 * lk + r] >= n1) ? 1 : 0;

                #pragma unroll
                for (int nt1 = 0; nt1 < 2; nt1++) {
                    const int c = 16 * nt1 + l15;
                    h8 b0f = {}, b1f = {};
                    if (lk < 2) {
                        b0f = *(const h8*)&sm.e.w1t[0][c][8 * lk];
                        b1f = *(const h8*)&sm.e.w1t[1][c][8 * lk];
                    }
                    f4 d0 = __builtin_amdgcn_mfma_f32_16x16x32_f16(a, b0f, zf4, 0, 0, 0);
                    f4 d1 = __builtin_amdgcn_mfma_f32_16x16x32_f16(a, b1f, zf4, 0, 0, 0);
                    #pragma unroll
                    for (int r = 0; r < 4; r++) {
                        int gp = 16 * mt + 4 * lk + r;
                        float hv = fast_tanh((j_r[r] ? d1[r] : d0[r]) + (j_r[r] ? b1r[1][nt1] : b1r[0][nt1]));
                        int e = 16 * nt1 + l15;
                        sm.e.s_h1[gp][(((e >> 3) ^ ((gp >> 1) & 3)) << 3) + (e & 7)] = (_Float16)hv;
                    }
                }
                asm volatile("" ::: "memory");

                h8 a2 = *(const h8*)&sm.e.s_h1[row][((lk ^ ((row >> 1) & 3)) << 3)];
                float cfv[4][4];
                #pragma unroll
                for (int k = 0; k < 4; k++) {
                    #pragma unroll
                    for (int r = 0; r < 4; r++)
                        cfv[k][r] = (float)sm.e.s_cf[k][t128 + 16 * mt + 4 * lk + r];
                }
                #pragma unroll
                for (int nt = 0; nt < 4; nt++) {
                    h8 w20 = *(const h8*)&sm.e.w2t[0][16 * nt + l15][8 * lk];
                    h8 w21 = *(const h8*)&sm.e.w2t[1][16 * nt + l15][8 * lk];
                    f4 e0 = __builtin_amdgcn_mfma_f32_16x16x32_f16(a2, w20, zf4, 0, 0, 0);
                    f4 e1 = __builtin_amdgcn_mfma_f32_16x16x32_f16(a2, w21, zf4, 0, 0, 0);
                    #pragma unroll
                    for (int r = 0; r < 4; r++) {
                        float ev = fast_tanh((j_r[r] ? e1[r] : e0[r]) + (j_r[r] ? b2r[1][nt] : b2r[0][nt]));
                        #pragma unroll
                        for (int k = 0; k < 4; k++)
                            gk[k][nt] = fmaf(cfv[k][r], ev, gk[k][nt]);
                    }
                }
            }
        }

        #pragma unroll
        for (int k = 0; k < 4; k++) {
            #pragma unroll
            for (int nt = 0; nt < 4; nt++) {
                float v = gk[k][nt];
                v += __shfl_xor(v, 16);
                v += __shfl_xor(v, 32);
                if (lane < 16) sm.e.s_g[wid][k][nt * 16 + lane] = v;
            }
        }
        __syncthreads();
        {
            int k = tid >> 6, c = tid & 63;
            float g = (sm.e.s_g[0][k][c] + sm.e.s_g[1][k][c]) + (sm.e.s_g[2][k][c] + sm.e.s_g[3][k][c]);
            g *= (1.0f / 64.0f);
            if (k == 0) g += Gbias[c];
            sm.e.s_g4[k * 64 + c] = g;
        }
        __syncthreads();
        {
            h2v* outp = feat + (size_t)n * 512;
            #pragma unroll
            for (int q = 0; q < 2; q++) {
                int o2 = tid + 256 * q;
                int a = o2 >> 5, c = (2 * o2) & 63;
                float ga0 = sm.e.s_g4[a],       ga1 = sm.e.s_g4[64 + a];
                float ga2 = sm.e.s_g4[128 + a], ga3 = sm.e.s_g4[192 + a];
                float s0 = ga0 * sm.e.s_g4[c];
                s0 = fmaf(ga1, sm.e.s_g4[64 + c],  s0);
                s0 = fmaf(ga2, sm.e.s_g4[128 + c], s0);
                s0 = fmaf(ga3, sm.e.s_g4[192 + c], s0);
                float s1 = ga0 * sm.e.s_g4[c + 1];
                s1 = fmaf(ga1, sm.e.s_g4[64 + c + 1],  s1);
                s1 = fmaf(ga2, sm.e.s_g4[128 + c + 1], s1);
                s1 = fmaf(ga3, sm.e.s_g4[192 + c + 1], s1);
                outp[o2] = pkh(s0, s1);
            }
        }
    }

    // ---- prep fold: blocks 0..287 transpose fit weights after their atom ---
    if (blockIdx.x < 288) {
        __syncthreads();   // done reading sm.e; reuse as s_t
        const int b = blockIdx.x;
        if (b == 0 && tid == 0) *counter = 0u;   // reset k_fit slot counter
        if (b < 256) {
            int type = b >> 7, tb = b & 127;
            int ki = tb >> 2, ci = tb & 3;
            const float* src = fW0 + (size_t)type * 131072;
            int c = tid & 31, r0 = (tid >> 5) * 4;
            #pragma unroll
            for (int q = 0; q < 4; q++)
                sm.s_t[r0 + q][c] = src[(size_t)(ki * 32 + r0 + q) * 128 + ci * 32 + c];
            __syncthreads();
            _Float16* dst = W0ht + (size_t)type * 131072;
            int kk = tid & 31, c0 = (tid >> 5) * 4;
            #pragma unroll
            for (int q = 0; q < 4; q++)
                dst[(size_t)(ci * 32 + c0 + q) * 1024 + ki * 32 + kk] = (_Float16)sm.s_t[kk][c0 + q];
        } else {
            int b2v = b - 256, type = b2v >> 4, tb = b2v & 15;
            int ki = tb >> 2, ci = tb & 3;
            const float* src = fW1 + (size_t)type * 16384;
            int c = tid & 31, r0 = (tid >> 5) * 4;
            #pragma unroll
            for (int q = 0; q < 4; q++)
                sm.s_t[r0 + q][c] = src[(size_t)(ki * 32 + r0 + q) * 128 + ci * 32 + c];
            __syncthreads();
            _Float16* dst = W1ht + (size_t)type * 16384;
            int kk = tid & 31, c0 = (tid >> 5) * 4;
            #pragma unroll
            for (int q = 0; q < 4; q++)
                dst[(size_t)(ci * 32 + c0 + q) * 128 + ki * 32 + kk] = (_Float16)sm.s_t[kk][c0 + q];
        }
    }
}

// ---- Kernel 2: fit net, 64 blocks x 16 atoms (R14 version, unchanged) ----
__global__ __launch_bounds__(512) void k_fit(
    const _Float16* __restrict__ featf, const _Float16* __restrict__ W0ht,
    const _Float16* __restrict__ W1ht,
    const float* __restrict__ b0, const float* __restrict__ b1,
    const float* __restrict__ W2, const float* __restrict__ b2,
    const float* __restrict__ Ebias, const int* __restrict__ n1p,
    unsigned int* __restrict__ counter, float* __restrict__ slots,
    float* __restrict__ out)
{
    __shared__ float s_red[4][2][16][64];
    __shared__ __align__(16) _Float16 s_hd[16][128];
    __shared__ float s_sum[16][32];

    const int tid = threadIdx.x;
    const int lane = tid & 63, w = tid >> 6;
    const int kq = w >> 1, ch = w & 1;
    const int l15 = lane & 15, lk = lane >> 4;
    const int n0 = blockIdx.x * 16;
    const int ia = (n0 >= *n1p) ? 1 : 0;
    const f4 zf4 = {0.0f, 0.0f, 0.0f, 0.0f};

    const _Float16* Ap = featf + (size_t)(n0 + l15) * 1024 + kq * 256;
    const _Float16* B0 = W0ht + (size_t)ia * 131072 + kq * 256;
    f4 acc[4] = {zf4, zf4, zf4, zf4};
    #pragma unroll
    for (int ks = 0; ks < 8; ks++) {
        h8 a = *(const h8*)(Ap + ks * 32 + 8 * lk);
        #pragma unroll
        for (int nt = 0; nt < 4; nt++) {
            const int c = ch * 64 + nt * 16 + l15;
            h8 b = *(const h8*)(B0 + (size_t)c * 1024 + ks * 32 + 8 * lk);
            acc[nt] = __builtin_amdgcn_mfma_f32_16x16x32_f16(a, b, acc[nt], 0, 0, 0);
        }
    }
    #pragma unroll
    for (int nt = 0; nt < 4; nt++)
        #pragma unroll
        for (int r = 0; r < 4; r++)
            s_red[kq][ch][4 * lk + r][nt * 16 + l15] = acc[nt][r];
    __syncthreads();

    {
        const int row = tid >> 5, c0 = (tid & 31) * 4;
        const int chh = c0 >> 6, cl = c0 & 63;
        f4 v = *(const f4*)&s_red[0][chh][row][cl];
        v += *(const f4*)&s_red[1][chh][row][cl];
        v += *(const f4*)&s_red[2][chh][row][cl];
        v += *(const f4*)&s_red[3][chh][row][cl];
        #pragma unroll
        for (int q = 0; q < 4; q++) {
            int c = c0 + q;
            float h = fast_tanh(v[q] + b0[ia * 128 + c]);
            s_hd[row][(((c >> 3) ^ row) << 3) + (c & 7)] = (_Float16)h;
        }
    }
    __syncthreads();

    f4 acc1[4] = {zf4, zf4, zf4, zf4};
    {
        h8 a = *(const h8*)&s_hd[l15][(((4 * kq + lk) ^ l15) & 15) << 3];
        const _Float16* B1 = W1ht + (size_t)ia * 16384 + kq * 32;
        #pragma unroll
        for (int nt = 0; nt < 4; nt++) {
            const int c = ch * 64 + nt * 16 + l15;
            h8 b = *(const h8*)(B1 + (size_t)c * 128 + 8 * lk);
            acc1[nt] = __builtin_amdgcn_mfma_f32_16x16x32_f16(a, b, zf4, 0, 0, 0);
        }
    }
    #pragma unroll
    for (int nt = 0; nt < 4; nt++)
        #pragma unroll
        for (int r = 0; r < 4; r++)
            s_red[kq][ch][4 * lk + r][nt * 16 + l15] = acc1[nt][r];
    __syncthreads();

    {
        const int row = tid >> 5, c0 = (tid & 31) * 4;
        const int chh = c0 >> 6, cl = c0 & 63;
        f4 v = *(const f4*)&s_red[0][chh][row][cl];
        v += *(const f4*)&s_red[1][chh][row][cl];
        v += *(const f4*)&s_red[2][chh][row][cl];
        v += *(const f4*)&s_red[3][chh][row][cl];
        float pv = 0.0f;
        #pragma unroll
        for (int q = 0; q < 4; q++) {
            int c = c0 + q;
            pv += fast_tanh(v[q] + b1[ia * 128 + c]) * W2[ia * 128 + c];
        }
        s_sum[row][tid & 31] = pv;
    }
    __syncthreads();
    if (w == 0) {
        const int row = lane >> 2, g = lane & 3;
        float s = 0.0f;
        #pragma unroll
        for (int i = 0; i < 8; i++) s += s_sum[row][8 * g + i];
        s += __shfl_xor(s, 1);  s += __shfl_xor(s, 2);
        s += __shfl_xor(s, 4);  s += __shfl_xor(s, 8);
        s += __shfl_xor(s, 16); s += __shfl_xor(s, 32);
        if (lane == 0) {
            float e = s + 16.0f * (b2[ia] + Ebias[ia]);
            slots[blockIdx.x] = e;
            __threadfence();
            unsigned int old = atomicAdd(counter, 1u);
            if (old == 63u) {
                __threadfence();
                float tot = 0.0f;
                for (int i = 0; i < 64; i++)
                    tot += __hip_atomic_load(&slots[i], __ATOMIC_RELAXED, __HIP_MEMORY_SCOPE_AGENT);
                out[0] = tot;
            }
        }
    }
}

extern "C" void kernel_launch(void* const* d_in, const int* in_sizes, int n_in,
                              void* d_out, int out_size, void* d_ws, size_t ws_size,
                              hipStream_t stream) {
    const float* coord   = (const float*)d_in[0];
    const float* box     = (const float*)d_in[1];
    const float* srmean  = (const float*)d_in[2];
    const float* srstd   = (const float*)d_in[3];
    const float* xrsrstd = (const float*)d_in[4];
    const float* Gbias   = (const float*)d_in[5];
    const float* Ebias   = (const float*)d_in[6];
    const float* eW0     = (const float*)d_in[7];
    const float* eb0     = (const float*)d_in[8];
    const float* eW1     = (const float*)d_in[9];
    const float* eb1     = (const float*)d_in[10];
    const float* eW2     = (const float*)d_in[11];
    const float* eb2     = (const float*)d_in[12];
    const float* fW0     = (const float*)d_in[13];
    const float* fb0     = (const float*)d_in[14];
    const float* fW1     = (const float*)d_in[15];
    const float* fb1     = (const float*)d_in[16];
    const float* fW2     = (const float*)d_in[17];
    const float* fb2     = (const float*)d_in[18];
    const int*   n1p     = (const int*)d_in[19];

    const int N = in_sizes[0] / 3;          // 1024
    h2v*      featbuf = (h2v*)d_ws;                                       // 2 MB
    _Float16* W0ht = (_Float16*)((char*)d_ws + (size_t)2 * 1024 * 1024);  // 512 KB
    _Float16* W1ht = W0ht + 2 * 131072;                                   // 64 KB
    char* tail = (char*)d_ws + (size_t)(2 * 1024 + 512 + 64) * 1024;
    unsigned int* counter = (unsigned int*)tail;
    float*        slots   = (float*)(tail + 64);

    k_embed<<<N, 256, 0, stream>>>(coord, box, srmean, srstd, xrsrstd,
                                   Gbias, eW0, eb0, eW1, eb1, eW2, eb2,
                                   n1p, fW0, fW1, featbuf, W0ht, W1ht,
                                   counter, N);
    k_fit<<<N / 16, 512, 0, stream>>>((const _Float16*)featbuf, W0ht, W1ht,
                                      fb0, fb1, fW2, fb2, Ebias, n1p,
                                      counter, slots, (float*)d_out);
}